// Round 8
// baseline (659.162 us; speedup 1.0000x reference)
//
#include <hip/hip_runtime.h>
#include <math.h>

// Problem constants
#define NN 50000
#define NE 500000
#define HC 128      // HEADS*OUT_CH
#define TD 64       // TIME_DIM
#define TILE_E 64   // edges per block in eproj
#define PXS 136     // x/msg LDS row stride bf16: 272B (16B-aligned), 68 words = 4 mod 32 banks (2-way, free)
#define NSCAN 25    // ceil(NN / 2048) scan blocks

typedef __attribute__((ext_vector_type(8))) short bf16x8;
typedef __attribute__((ext_vector_type(4))) float f32x4;

__device__ __forceinline__ short f2bf(float f) {
    union { float f; unsigned u; } a; a.f = f;
    unsigned r = a.u + 0x7fff + ((a.u >> 16) & 1);   // RNE
    return (short)(r >> 16);
}
__device__ __forceinline__ float bf2f(short s) {
    union { unsigned u; float f; } a; a.u = ((unsigned)(unsigned short)s) << 16;
    return a.f;
}

// ---------------------------------------------------------------------------
// prep (fused): We_msg^T (128x128), WT (4x128x128), dst histogram
// ---------------------------------------------------------------------------
__global__ __launch_bounds__(256) void prep_all(
    const float* __restrict__ We,
    const float* __restrict__ Wq, const float* __restrict__ Wk,
    const float* __restrict__ Wv, const float* __restrict__ Ws,
    short* __restrict__ WmT, short* __restrict__ WT,
    const int* __restrict__ ei, int* __restrict__ cnt)
{
    int i = blockIdx.x * 256 + threadIdx.x;
    if (i < HC * 128) {   // WmT[n][kk] = We[(TD+kk)][n]  (msg rows of We)
        int n = i >> 7, kk = i & 127;
        WmT[i] = f2bf(We[(size_t)(TD + kk) * HC + n]);
        return;
    }
    int j = i - HC * 128;
    if (j < 4 * 128 * 128) {
        int m = j >> 14, r = j & 16383, n = r >> 7, kk = r & 127;
        const float* W = (m == 0) ? Wq : (m == 1) ? Wk : (m == 2) ? Wv : Ws;
        WT[j] = f2bf(W[kk * 128 + n]);
        return;
    }
    int e = j - 4 * 128 * 128;
    if (e < NE) atomicAdd(&cnt[ei[NE + e]], 1);
}

// ---------------------------------------------------------------------------
// Counting sort by dst: scan1 -> scan2(+poly coeffs) -> scatter
// scatter outputs: srcs_sorted[pos] = src, rank[orig_e] = pos
// ---------------------------------------------------------------------------
__global__ __launch_bounds__(256) void scan1(const int* __restrict__ cnt,
                                             int* __restrict__ cursor,
                                             int* __restrict__ bsum) {
    __shared__ int ts[256];
    int b = blockIdx.x, t = threadIdx.x;
    int base = b * 2048 + t * 8;
    int v[8], tot = 0;
#pragma unroll
    for (int i = 0; i < 8; i++) {
        int x = (base + i < NN) ? cnt[base + i] : 0;
        v[i] = tot; tot += x;
    }
    ts[t] = tot;
    __syncthreads();
    for (int off = 1; off < 256; off <<= 1) {
        int y = (t >= off) ? ts[t - off] : 0;
        __syncthreads();
        ts[t] += y;
        __syncthreads();
    }
    int texcl = ts[t] - tot;   // exclusive prefix of this thread within block
#pragma unroll
    for (int i = 0; i < 8; i++)
        if (base + i < NN) cursor[base + i] = v[i] + texcl;
    if (t == 255) bsum[b] = ts[255];
}

// scan2 (1 block, 128 threads): bsum exclusive scan + time-encoding Taylor
// coefficients in fragment-layout float4.
__global__ void scan2(int* __restrict__ bsum,
                      const float* __restrict__ time_w,
                      const float* __restrict__ time_b,
                      const float* __restrict__ We,
                      float* __restrict__ Apoly) {
    int t = threadIdx.x;
    if (t == 0) {
        int acc = 0;
        for (int i = 0; i < NSCAN; i++) { int x = bsum[i]; bsum[i] = acc; acc += x; }
    }
    if (t < 128) {
        int n = t, h = n >> 6, nt = (n >> 4) & 3, cc = n & 15;
        float s0 = 0.f, s1 = 0.f, s2 = 0.f, s3 = 0.f, s4 = 0.f;
        for (int j = 0; j < TD; j++) {
            float w  = time_w[j], b = time_b[j];
            float cb = __cosf(b), sb = __sinf(b);
            float we = We[(size_t)j * HC + n];
            float w2 = w * w;
            s0 += cb * we;
            s1 -= w * sb * we;
            s2 -= 0.5f * w2 * cb * we;
            s3 += (w2 * w * (1.0f / 6.0f)) * sb * we;
            s4 += (w2 * w2 * (1.0f / 24.0f)) * cb * we;
        }
        int fi = (h * 16 + cc) * 4 + nt;
        Apoly[(0 * 32) * 4 + fi] = s0;
        Apoly[(1 * 32) * 4 + fi] = s1;
        Apoly[(2 * 32) * 4 + fi] = s2;
        Apoly[(3 * 32) * 4 + fi] = s3;
        Apoly[(4 * 32) * 4 + fi] = s4;
    }
}

__global__ __launch_bounds__(256) void scatter_kernel(
    const int* __restrict__ ei, int* __restrict__ cursor,
    const int* __restrict__ bsum,
    int* __restrict__ srcs, int* __restrict__ rank) {
    int e = blockIdx.x * 256 + threadIdx.x;
    if (e >= NE) return;
    int s = ei[e], d = ei[NE + e];
    int pos = atomicAdd(&cursor[d], 1) + bsum[d >> 11];
    srcs[pos] = s;
    rank[e]   = pos;
}

// ---------------------------------------------------------------------------
// K1: MFMA projections. Stages x (fp32->bf16 in-register) directly; A
// preloaded from LDS; B per-nt batches of 4. q/k/v stored bf16 in
// BOTH-HEADS-PER-LANE layout: qb[(n*16 + c)*8 + nt] = ch(nt*16+c), nt=0..7.
// ---------------------------------------------------------------------------
__global__ __launch_bounds__(256) void proj_mfma(
    const float* __restrict__ x,      // [NN][128] f32
    const short* __restrict__ WT,     // [4][128][128] bf16 (n-major)
    const float* __restrict__ bq, const float* __restrict__ bk,
    const float* __restrict__ bv, const float* __restrict__ bs,
    short* __restrict__ qb, short* __restrict__ kb, short* __restrict__ vb,
    float* __restrict__ skip)
{
    __shared__ short xs[32 * PXS];   // 8.7 KB
    const int t  = threadIdx.x;
    const int n0 = blockIdx.x * 32;

    // batched staging: 4 float4 loads in flight, then convert+LDS
    float4 xreg[4];
#pragma unroll
    for (int j = 0; j < 4; j++) {
        int idx = t + j * 256;           // over 32*32 float4s
        int m   = idx >> 5;
        int c4  = idx & 31;
        int n   = n0 + m;
        float4 v = {0.f, 0.f, 0.f, 0.f};
        if (n < NN) v = ((const float4*)x)[(size_t)n * 32 + c4];
        xreg[j] = v;
    }
#pragma unroll
    for (int j = 0; j < 4; j++) {
        int idx = t + j * 256;
        int m   = idx >> 5;
        int c4  = idx & 31;
        short4 o;
        o.x = f2bf(xreg[j].x); o.y = f2bf(xreg[j].y);
        o.z = f2bf(xreg[j].z); o.w = f2bf(xreg[j].w);
        *(short4*)&xs[m * PXS + c4 * 4] = o;
    }
    __syncthreads();

    const int w    = t >> 6;
    const int lane = t & 63;
    const int c    = lane & 15;
    const int qd   = lane >> 4;
    const short* WTm = WT + (size_t)w * 16384;

    // preload A-fragments (8 ds_read_b128)
    bf16x8 a0[4], a1[4];
#pragma unroll
    for (int kb2 = 0; kb2 < 4; kb2++) {
        a0[kb2] = *(const bf16x8*)&xs[c * PXS + qd * 8 + kb2 * 32];
        a1[kb2] = *(const bf16x8*)&xs[(16 + c) * PXS + qd * 8 + kb2 * 32];
    }

    f32x4 acc[2][8];
#pragma unroll
    for (int mt = 0; mt < 2; mt++)
#pragma unroll
        for (int nt = 0; nt < 8; nt++) acc[mt][nt] = (f32x4){0.f, 0.f, 0.f, 0.f};

#pragma unroll
    for (int nt = 0; nt < 8; nt++) {
        bf16x8 bw[4];
#pragma unroll
        for (int kb2 = 0; kb2 < 4; kb2++)
            bw[kb2] = *(const bf16x8*)&WTm[(size_t)(nt * 16 + c) * 128 + qd * 8 + kb2 * 32];
#pragma unroll
        for (int kb2 = 0; kb2 < 4; kb2++) {
            acc[0][nt] = __builtin_amdgcn_mfma_f32_16x16x32_bf16(a0[kb2], bw[kb2], acc[0][nt], 0, 0, 0);
            acc[1][nt] = __builtin_amdgcn_mfma_f32_16x16x32_bf16(a1[kb2], bw[kb2], acc[1][nt], 0, 0, 0);
        }
    }

    const float* bias = (w == 0) ? bq : (w == 1) ? bk : (w == 2) ? bv : bs;
    float bvals[8];
#pragma unroll
    for (int nt = 0; nt < 8; nt++) bvals[nt] = bias[nt * 16 + c];

    if (w < 3) {
        short* dstb = (w == 0) ? qb : (w == 1) ? kb : vb;
#pragma unroll
        for (int mt = 0; mt < 2; mt++) {
#pragma unroll
            for (int r = 0; r < 4; r++) {
                int n = n0 + mt * 16 + qd * 4 + r;
                if (n < NN) {
                    bf16x8 o;
#pragma unroll
                    for (int nt = 0; nt < 8; nt++)
                        o[nt] = f2bf(acc[mt][nt][r] + bvals[nt]);
                    ((bf16x8*)dstb)[(size_t)n * 16 + c] = o;
                }
            }
        }
    } else {
#pragma unroll
        for (int mt = 0; mt < 2; mt++) {
#pragma unroll
            for (int r = 0; r < 4; r++) {
                int n = n0 + mt * 16 + qd * 4 + r;
                if (n < NN) {
                    float* dp = skip + (size_t)n * HC + c;
#pragma unroll
                    for (int nt = 0; nt < 8; nt++)
                        dp[nt * 16] = acc[mt][nt][r] + bvals[nt];
                }
            }
        }
    }
}

// ---------------------------------------------------------------------------
// K2a: e-projection, original edge order (streaming msg), K=128, Taylor time
// encoding. Output written at SORTED position rank[e], layout
// e_buf[pos][h][c][nt4] (shorts: pos*128 + h*64 + c*4 + nt): each 16-lane
// group stores 128B CONTIGUOUS per (edge, head) -- full-line scattered
// writes, no partial-line RMW. attn reads e_buf sequentially.
// ---------------------------------------------------------------------------
__global__ __launch_bounds__(256) void eproj_kernel(
    const int*   __restrict__ ei,
    const float* __restrict__ tarr,
    const float* __restrict__ lastup,
    const float* __restrict__ msg,
    const short* __restrict__ WmT,      // [128][128] bf16 (n-major)
    const float* __restrict__ Apoly,    // [5][32] float4 fragment layout
    const int*   __restrict__ rank,
    short* __restrict__ e_buf)          // [NE][2][16][4] bf16 (sorted order)
{
    __shared__ short mg[TILE_E * PXS];  // 17.4 KB
    __shared__ float relt[TILE_E];
    __shared__ int   rks[TILE_E];

    const int t  = threadIdx.x;
    const int e0 = blockIdx.x * TILE_E;

    const int w    = t >> 6;
    const int h    = w >> 1;
    const int half = w & 1;
    const int lane = t & 63;
    const int qd   = lane >> 4;
    const int c    = lane & 15;
    const int hb   = h * 64;

    // issue Apoly loads early (in flight through staging + MFMA)
    const float4* Ap = (const float4*)Apoly;
    float4 A0 = Ap[0 * 32 + h * 16 + c];
    float4 A1 = Ap[1 * 32 + h * 16 + c];
    float4 A2 = Ap[2 * 32 + h * 16 + c];
    float4 A3 = Ap[3 * 32 + h * 16 + c];
    float4 A4 = Ap[4 * 32 + h * 16 + c];

    if (t < TILE_E) {
        int eg = e0 + t;
        float rt = 0.f;
        int rk = 0;
        if (eg < NE) {
            rt = tarr[eg] - lastup[ei[eg]];
            rk = rank[eg];
        }
        relt[t] = rt;
        rks[t]  = rk;
    }

    // --- batched staging: 8 float4 loads issued together, then convert ---
    float4 mreg[8];
#pragma unroll
    for (int j = 0; j < 8; j++) {
        int idx = t + j * 256;
        int le  = idx >> 5;
        int c4  = idx & 31;
        float4 m = {0.f, 0.f, 0.f, 0.f};
        if (e0 + le < NE) m = ((const float4*)msg)[(size_t)(e0 + le) * 32 + c4];
        mreg[j] = m;
    }
#pragma unroll
    for (int j = 0; j < 8; j++) {
        int idx = t + j * 256;
        int le  = idx >> 5;
        int c4  = idx & 31;
        int li  = le & 31;
        int row = (le & 32) + ((li & 7) >> 2) * 16 + (li >> 3) * 4 + (li & 3);
        short4 pm;
        pm.x = f2bf(mreg[j].x); pm.y = f2bf(mreg[j].y);
        pm.z = f2bf(mreg[j].z); pm.w = f2bf(mreg[j].w);
        *(short4*)&mg[row * PXS + 4 * c4] = pm;
    }
    __syncthreads();

    // --- preload A-fragments (8 ds_read_b128) ---
    bf16x8 a[2][4];
#pragma unroll
    for (int mt = 0; mt < 2; mt++)
#pragma unroll
        for (int kb2 = 0; kb2 < 4; kb2++)
            a[mt][kb2] = *(const bf16x8*)&mg[(half * 32 + mt * 16 + c) * PXS + qd * 8 + kb2 * 32];

    f32x4 acc[2][4];
#pragma unroll
    for (int mt = 0; mt < 2; mt++)
#pragma unroll
        for (int nt = 0; nt < 4; nt++) acc[mt][nt] = (f32x4){0.f, 0.f, 0.f, 0.f};

    const short* bP = &WmT[(size_t)(hb + c) * 128 + qd * 8];
#pragma unroll
    for (int nt = 0; nt < 4; nt++) {
        bf16x8 bw[4];
#pragma unroll
        for (int kb2 = 0; kb2 < 4; kb2++)
            bw[kb2] = *(const bf16x8*)(bP + (size_t)(nt * 16) * 128 + kb2 * 32);
#pragma unroll
        for (int kb2 = 0; kb2 < 4; kb2++) {
            acc[0][nt] = __builtin_amdgcn_mfma_f32_16x16x32_bf16(a[0][kb2], bw[kb2], acc[0][nt], 0, 0, 0);
            acc[1][nt] = __builtin_amdgcn_mfma_f32_16x16x32_bf16(a[1][kb2], bw[kb2], acc[1][nt], 0, 0, 0);
        }
    }

    // --- epilogue: Taylor time-encoding + full-line store at rank position ---
#pragma unroll
    for (int mt = 0; mt < 2; mt++) {
#pragma unroll
        for (int r = 0; r < 4; r++) {
            int le = half * 32 + qd * 8 + mt * 4 + r;
            int eg = e0 + le;
            if (eg < NE) {
                float rt = relt[le];
                int   rk = rks[le];
                float w0 = A0.x + rt * (A1.x + rt * (A2.x + rt * (A3.x + rt * A4.x)));
                float w1 = A0.y + rt * (A1.y + rt * (A2.y + rt * (A3.y + rt * A4.y)));
                float w2 = A0.z + rt * (A1.z + rt * (A2.z + rt * (A3.z + rt * A4.z)));
                float w3 = A0.w + rt * (A1.w + rt * (A2.w + rt * (A3.w + rt * A4.w)));
                short4 o;
                o.x = f2bf(acc[mt][0][r] + w0);
                o.y = f2bf(acc[mt][1][r] + w1);
                o.z = f2bf(acc[mt][2][r] + w2);
                o.w = f2bf(acc[mt][3][r] + w3);
                // 16 lanes (c=0..15) -> 128B contiguous at pos*256 + h*128
                *(short4*)&e_buf[(size_t)rk * 128 + h * 64 + c * 4] = o;
            }
        }
    }
}

// ---------------------------------------------------------------------------
// K2b: node-centric attention, both heads per lane. 16 lanes per node; per
// edge: 1 scalar src + k(16B) + v(16B) gathers + e 2x8B SEQUENTIAL loads.
// Zero atomics, finalize fused.
// ---------------------------------------------------------------------------
__device__ __forceinline__ void edge_acc16(
    bf16x8 k8, bf16x8 v8, short4 e0, short4 e1, const float* qf,
    float* a, float& as0, float& as1)
{
    float ev0[4], ev1[4];
    ev0[0] = bf2f(e0.x); ev0[1] = bf2f(e0.y); ev0[2] = bf2f(e0.z); ev0[3] = bf2f(e0.w);
    ev1[0] = bf2f(e1.x); ev1[1] = bf2f(e1.y); ev1[2] = bf2f(e1.z); ev1[3] = bf2f(e1.w);
    float p0 = qf[0] * (bf2f(k8[0]) + ev0[0]) + qf[1] * (bf2f(k8[1]) + ev0[1])
             + qf[2] * (bf2f(k8[2]) + ev0[2]) + qf[3] * (bf2f(k8[3]) + ev0[3]);
    float p1 = qf[4] * (bf2f(k8[4]) + ev1[0]) + qf[5] * (bf2f(k8[5]) + ev1[1])
             + qf[6] * (bf2f(k8[6]) + ev1[2]) + qf[7] * (bf2f(k8[7]) + ev1[3]);
    p0 += __shfl_xor(p0, 1); p1 += __shfl_xor(p1, 1);
    p0 += __shfl_xor(p0, 2); p1 += __shfl_xor(p1, 2);
    p0 += __shfl_xor(p0, 4); p1 += __shfl_xor(p1, 4);
    p0 += __shfl_xor(p0, 8); p1 += __shfl_xor(p1, 8);
    float al0 = __expf(p0 * 0.125f);   // 1/sqrt(64)
    float al1 = __expf(p1 * 0.125f);
    a[0] += (bf2f(v8[0]) + ev0[0]) * al0;
    a[1] += (bf2f(v8[1]) + ev0[1]) * al0;
    a[2] += (bf2f(v8[2]) + ev0[2]) * al0;
    a[3] += (bf2f(v8[3]) + ev0[3]) * al0;
    a[4] += (bf2f(v8[4]) + ev1[0]) * al1;
    a[5] += (bf2f(v8[5]) + ev1[1]) * al1;
    a[6] += (bf2f(v8[6]) + ev1[2]) * al1;
    a[7] += (bf2f(v8[7]) + ev1[3]) * al1;
    as0 += al0; as1 += al1;
}

__global__ __launch_bounds__(256) void attn_node(
    const int*   __restrict__ srcs,
    const short* __restrict__ qb,
    const short* __restrict__ kb,
    const short* __restrict__ vb,
    const short* __restrict__ e_buf,    // sorted order [pos][h][c][nt4]
    const int*   __restrict__ cnt,
    const int*   __restrict__ cursor,   // post-scatter: start+cnt (chunk-local)
    const int*   __restrict__ bsum,
    const float* __restrict__ skip,
    float* __restrict__ out)
{
    const int t = threadIdx.x;
    const int g = t >> 4;
    const int c = t & 15;
    const int n = blockIdx.x * 16 + g;   // 3125*16 = 50000 exact

    const int deg   = cnt[n];
    const int start = cursor[n] + bsum[n >> 11] - deg;

    bf16x8 q8 = ((const bf16x8*)qb)[(size_t)n * 16 + c];
    float qf[8];
#pragma unroll
    for (int j = 0; j < 8; j++) qf[j] = bf2f(q8[j]);

    float a[8] = {0.f, 0.f, 0.f, 0.f, 0.f, 0.f, 0.f, 0.f};
    float as0 = 0.f, as1 = 0.f;

    const short4* ebp = (const short4*)e_buf;   // 32 short4 per edge

    int i = 0;
    for (; i + 4 <= deg; i += 4) {
        int s0 = srcs[start + i];
        int s1 = srcs[start + i + 1];
        int s2 = srcs[start + i + 2];
        int s3 = srcs[start + i + 3];
        bf16x8 kA = ((const bf16x8*)kb)[(size_t)s0 * 16 + c];
        bf16x8 vA = ((const bf16x8*)vb)[(size_t)s0 * 16 + c];
        short4 e0A = ebp[(size_t)(start + i) * 32 + c];
        short4 e1A = ebp[(size_t)(start + i) * 32 + 16 + c];
        bf16x8 kB = ((const bf16x8*)kb)[(size_t)s1 * 16 + c];
        bf16x8 vB = ((const bf16x8*)vb)[(size_t)s1 * 16 + c];
        short4 e0B = ebp[(size_t)(start + i + 1) * 32 + c];
        short4 e1B = ebp[(size_t)(start + i + 1) * 32 + 16 + c];
        bf16x8 kC = ((const bf16x8*)kb)[(size_t)s2 * 16 + c];
        bf16x8 vC = ((const bf16x8*)vb)[(size_t)s2 * 16 + c];
        short4 e0C = ebp[(size_t)(start + i + 2) * 32 + c];
        short4 e1C = ebp[(size_t)(start + i + 2) * 32 + 16 + c];
        bf16x8 kD = ((const bf16x8*)kb)[(size_t)s3 * 16 + c];
        bf16x8 vD = ((const bf16x8*)vb)[(size_t)s3 * 16 + c];
        short4 e0D = ebp[(size_t)(start + i + 3) * 32 + c];
        short4 e1D = ebp[(size_t)(start + i + 3) * 32 + 16 + c];
        edge_acc16(kA, vA, e0A, e1A, qf, a, as0, as1);
        edge_acc16(kB, vB, e0B, e1B, qf, a, as0, as1);
        edge_acc16(kC, vC, e0C, e1C, qf, a, as0, as1);
        edge_acc16(kD, vD, e0D, e1D, qf, a, as0, as1);
    }
    for (; i < deg; i++) {
        int s0 = srcs[start + i];
        bf16x8 kA = ((const bf16x8*)kb)[(size_t)s0 * 16 + c];
        bf16x8 vA = ((const bf16x8*)vb)[(size_t)s0 * 16 + c];
        short4 e0A = ebp[(size_t)(start + i) * 32 + c];
        short4 e1A = ebp[(size_t)(start + i) * 32 + 16 + c];
        edge_acc16(kA, vA, e0A, e1A, qf, a, as0, as1);
    }

    float inv0 = 1.0f / (as0 + 1e-16f);
    float inv1 = 1.0f / (as1 + 1e-16f);
    size_t ob = (size_t)n * HC + c;
#pragma unroll
    for (int nt = 0; nt < 4; nt++)
        out[ob + nt * 16] = a[nt] * inv0 + skip[ob + nt * 16];
#pragma unroll
    for (int nt = 4; nt < 8; nt++)
        out[ob + nt * 16] = a[nt] * inv1 + skip[ob + nt * 16];
}

// ---------------------------------------------------------------------------
extern "C" void kernel_launch(void* const* d_in, const int* in_sizes, int n_in,
                              void* d_out, int out_size, void* d_ws, size_t ws_size,
                              hipStream_t stream) {
    const float* x      = (const float*)d_in[0];
    const float* lastup = (const float*)d_in[1];
    const float* tarr   = (const float*)d_in[2];
    const float* msg    = (const float*)d_in[3];
    const float* time_w = (const float*)d_in[4];
    const float* time_b = (const float*)d_in[5];
    const float* Wq     = (const float*)d_in[6];
    const float* bq     = (const float*)d_in[7];
    const float* Wk     = (const float*)d_in[8];
    const float* bk     = (const float*)d_in[9];
    const float* Wv     = (const float*)d_in[10];
    const float* bv     = (const float*)d_in[11];
    const float* We     = (const float*)d_in[12];
    const float* Wskip  = (const float*)d_in[13];
    const float* bskip  = (const float*)d_in[14];
    const int*   ei     = (const int*)d_in[15];

    // ws layout: skip f32 | Apoly f32 | srcs int | rank int | WmT | WT |
    //            qb | kb | vb | e_buf bf16 | cnt | cursor | bsum (int)
    float* ws    = (float*)d_ws;
    float* skip  = ws;
    float* Apoly = skip + (size_t)NN * HC;
    int*   srcs  = (int*)(Apoly + 5 * 128);
    int*   rank  = srcs + NE;
    short* WmT   = (short*)(rank + NE);
    short* WT    = WmT + (size_t)HC * 128;
    short* qb    = WT + (size_t)4 * 128 * 128;
    short* kb    = qb + (size_t)NN * HC;
    short* vb    = kb + (size_t)NN * HC;
    short* e_buf = vb + (size_t)NN * HC;
    int*   cnt    = (int*)(e_buf + (size_t)NE * HC);
    int*   cursor = cnt + NN;
    int*   bsum   = cursor + NN;
    float* out  = (float*)d_out;

    // --- prep (+fused histogram) ---
    hipMemsetAsync(cnt, 0, (size_t)NN * sizeof(int), stream);
    prep_all<<<dim3((HC * 128 + 4 * 128 * 128 + NE + 255) / 256), 256, 0, stream>>>(
        We, Wq, Wk, Wv, Wskip, WmT, WT, ei, cnt);

    // --- counting sort by dst (srcs + inverse perm; coeffs piggyback scan2) ---
    scan1<<<dim3(NSCAN), 256, 0, stream>>>(cnt, cursor, bsum);
    scan2<<<dim3(1), 128, 0, stream>>>(bsum, time_w, time_b, We, Apoly);
    scatter_kernel<<<dim3((NE + 255) / 256), 256, 0, stream>>>(
        ei, cursor, bsum, srcs, rank);

    proj_mfma<<<dim3((NN + 31) / 32), 256, 0, stream>>>(
        x, WT, bq, bk, bv, bskip, qb, kb, vb, skip);

    // --- e projection: streaming msg read, full-line rank-scattered write ---
    eproj_kernel<<<dim3((NE + TILE_E - 1) / TILE_E), 256, 0, stream>>>(
        ei, tarr, lastup, msg, WmT, Apoly, rank, e_buf);

    // --- node-centric attention: sequential e_buf, zero atomics ---
    attn_node<<<dim3(NN / 16), 256, 0, stream>>>(
        srcs, qb, kb, vb, e_buf, cnt, cursor, bsum, skip, out);
}

// Round 9
// 623.550 us; speedup vs baseline: 1.0571x; 1.0571x over previous
//
#include <hip/hip_runtime.h>
#include <math.h>

// Problem constants
#define NN 50000
#define NE 500000
#define HC 128      // HEADS*OUT_CH
#define TD 64       // TIME_DIM
#define TILE_E 64   // edges per block in eproj
#define PXS 136     // x/msg LDS row stride bf16: 272B (16B-aligned), 68 words = 4 mod 32 banks (2-way, free)
#define NSCAN 25    // ceil(NN / 2048) scan blocks

typedef __attribute__((ext_vector_type(8))) short bf16x8;
typedef __attribute__((ext_vector_type(4))) float f32x4;

__device__ __forceinline__ short f2bf(float f) {
    union { float f; unsigned u; } a; a.f = f;
    unsigned r = a.u + 0x7fff + ((a.u >> 16) & 1);   // RNE
    return (short)(r >> 16);
}
__device__ __forceinline__ float bf2f(short s) {
    union { unsigned u; float f; } a; a.u = ((unsigned)(unsigned short)s) << 16;
    return a.f;
}

// ---------------------------------------------------------------------------
// prep (fused): We_msg^T (128x128), WT (4x128x128), dst histogram
// ---------------------------------------------------------------------------
__global__ __launch_bounds__(256) void prep_all(
    const float* __restrict__ We,
    const float* __restrict__ Wq, const float* __restrict__ Wk,
    const float* __restrict__ Wv, const float* __restrict__ Ws,
    short* __restrict__ WmT, short* __restrict__ WT,
    const int* __restrict__ ei, int* __restrict__ cnt)
{
    int i = blockIdx.x * 256 + threadIdx.x;
    if (i < HC * 128) {   // WmT[n][kk] = We[(TD+kk)][n]  (msg rows of We)
        int n = i >> 7, kk = i & 127;
        WmT[i] = f2bf(We[(size_t)(TD + kk) * HC + n]);
        return;
    }
    int j = i - HC * 128;
    if (j < 4 * 128 * 128) {
        int m = j >> 14, r = j & 16383, n = r >> 7, kk = r & 127;
        const float* W = (m == 0) ? Wq : (m == 1) ? Wk : (m == 2) ? Wv : Ws;
        WT[j] = f2bf(W[kk * 128 + n]);
        return;
    }
    int e = j - 4 * 128 * 128;
    if (e < NE) atomicAdd(&cnt[ei[NE + e]], 1);
}

// ---------------------------------------------------------------------------
// Counting sort by dst: scan1 -> scan2(+poly coeffs, edata pad) -> scatter
// edata[pos] = (src, orig_edge)
// ---------------------------------------------------------------------------
__global__ __launch_bounds__(256) void scan1(const int* __restrict__ cnt,
                                             int* __restrict__ cursor,
                                             int* __restrict__ bsum) {
    __shared__ int ts[256];
    int b = blockIdx.x, t = threadIdx.x;
    int base = b * 2048 + t * 8;
    int v[8], tot = 0;
#pragma unroll
    for (int i = 0; i < 8; i++) {
        int x = (base + i < NN) ? cnt[base + i] : 0;
        v[i] = tot; tot += x;
    }
    ts[t] = tot;
    __syncthreads();
    for (int off = 1; off < 256; off <<= 1) {
        int y = (t >= off) ? ts[t - off] : 0;
        __syncthreads();
        ts[t] += y;
        __syncthreads();
    }
    int texcl = ts[t] - tot;   // exclusive prefix of this thread within block
#pragma unroll
    for (int i = 0; i < 8; i++)
        if (base + i < NN) cursor[base + i] = v[i] + texcl;
    if (t == 255) bsum[b] = ts[255];
}

// scan2 (1 block, 128 threads): bsum exclusive scan + time-encoding Taylor
// coefficients in fragment-layout float4 + edata tail pad (prefetch slack).
__global__ void scan2(int* __restrict__ bsum,
                      const float* __restrict__ time_w,
                      const float* __restrict__ time_b,
                      const float* __restrict__ We,
                      float* __restrict__ Apoly,
                      int2* __restrict__ edata) {
    int t = threadIdx.x;
    if (t == 0) {
        int acc = 0;
        for (int i = 0; i < NSCAN; i++) { int x = bsum[i]; bsum[i] = acc; acc += x; }
    }
    if (t < 16) edata[NE + t] = make_int2(0, 0);   // prefetch slack
    if (t < 128) {
        int n = t, h = n >> 6, nt = (n >> 4) & 3, cc = n & 15;
        float s0 = 0.f, s1 = 0.f, s2 = 0.f, s3 = 0.f, s4 = 0.f;
        for (int j = 0; j < TD; j++) {
            float w  = time_w[j], b = time_b[j];
            float cb = __cosf(b), sb = __sinf(b);
            float we = We[(size_t)j * HC + n];
            float w2 = w * w;
            s0 += cb * we;
            s1 -= w * sb * we;
            s2 -= 0.5f * w2 * cb * we;
            s3 += (w2 * w * (1.0f / 6.0f)) * sb * we;
            s4 += (w2 * w2 * (1.0f / 24.0f)) * cb * we;
        }
        int fi = (h * 16 + cc) * 4 + nt;
        Apoly[(0 * 32) * 4 + fi] = s0;
        Apoly[(1 * 32) * 4 + fi] = s1;
        Apoly[(2 * 32) * 4 + fi] = s2;
        Apoly[(3 * 32) * 4 + fi] = s3;
        Apoly[(4 * 32) * 4 + fi] = s4;
    }
}

__global__ __launch_bounds__(256) void scatter_kernel(
    const int* __restrict__ ei, int* __restrict__ cursor,
    const int* __restrict__ bsum, int2* __restrict__ edata) {
    int e = blockIdx.x * 256 + threadIdx.x;
    if (e >= NE) return;
    int s = ei[e], d = ei[NE + e];
    int pos = atomicAdd(&cursor[d], 1) + bsum[d >> 11];
    edata[pos] = make_int2(s, e);
}

// ---------------------------------------------------------------------------
// K1: MFMA projections. Stages x (fp32->bf16 in-register) directly; A
// preloaded from LDS; B per-nt batches of 4. q/k/v stored bf16 in
// head-separated fragment layout: [n][2][16][4] (round-6 layout).
// ---------------------------------------------------------------------------
__global__ __launch_bounds__(256) void proj_mfma(
    const float* __restrict__ x,      // [NN][128] f32
    const short* __restrict__ WT,     // [4][128][128] bf16 (n-major)
    const float* __restrict__ bq, const float* __restrict__ bk,
    const float* __restrict__ bv, const float* __restrict__ bs,
    short* __restrict__ qb, short* __restrict__ kb, short* __restrict__ vb,
    float* __restrict__ skip)
{
    __shared__ short xs[32 * PXS];   // 8.7 KB
    const int t  = threadIdx.x;
    const int n0 = blockIdx.x * 32;

    // batched staging: 4 float4 loads in flight, then convert+LDS
    float4 xreg[4];
#pragma unroll
    for (int j = 0; j < 4; j++) {
        int idx = t + j * 256;           // over 32*32 float4s
        int m   = idx >> 5;
        int c4  = idx & 31;
        int n   = n0 + m;
        float4 v = {0.f, 0.f, 0.f, 0.f};
        if (n < NN) v = ((const float4*)x)[(size_t)n * 32 + c4];
        xreg[j] = v;
    }
#pragma unroll
    for (int j = 0; j < 4; j++) {
        int idx = t + j * 256;
        int m   = idx >> 5;
        int c4  = idx & 31;
        short4 o;
        o.x = f2bf(xreg[j].x); o.y = f2bf(xreg[j].y);
        o.z = f2bf(xreg[j].z); o.w = f2bf(xreg[j].w);
        *(short4*)&xs[m * PXS + c4 * 4] = o;
    }
    __syncthreads();

    const int w    = t >> 6;
    const int lane = t & 63;
    const int c    = lane & 15;
    const int qd   = lane >> 4;
    const short* WTm = WT + (size_t)w * 16384;

    // preload A-fragments (8 ds_read_b128)
    bf16x8 a0[4], a1[4];
#pragma unroll
    for (int kb2 = 0; kb2 < 4; kb2++) {
        a0[kb2] = *(const bf16x8*)&xs[c * PXS + qd * 8 + kb2 * 32];
        a1[kb2] = *(const bf16x8*)&xs[(16 + c) * PXS + qd * 8 + kb2 * 32];
    }

    f32x4 acc[2][8];
#pragma unroll
    for (int mt = 0; mt < 2; mt++)
#pragma unroll
        for (int nt = 0; nt < 8; nt++) acc[mt][nt] = (f32x4){0.f, 0.f, 0.f, 0.f};

#pragma unroll
    for (int nt = 0; nt < 8; nt++) {
        bf16x8 bw[4];
#pragma unroll
        for (int kb2 = 0; kb2 < 4; kb2++)
            bw[kb2] = *(const bf16x8*)&WTm[(size_t)(nt * 16 + c) * 128 + qd * 8 + kb2 * 32];
#pragma unroll
        for (int kb2 = 0; kb2 < 4; kb2++) {
            acc[0][nt] = __builtin_amdgcn_mfma_f32_16x16x32_bf16(a0[kb2], bw[kb2], acc[0][nt], 0, 0, 0);
            acc[1][nt] = __builtin_amdgcn_mfma_f32_16x16x32_bf16(a1[kb2], bw[kb2], acc[1][nt], 0, 0, 0);
        }
    }

    const float* bias = (w == 0) ? bq : (w == 1) ? bk : (w == 2) ? bv : bs;
    float bvals[8];
#pragma unroll
    for (int nt = 0; nt < 8; nt++) bvals[nt] = bias[nt * 16 + c];

    if (w < 3) {
        short* dstb = (w == 0) ? qb : (w == 1) ? kb : vb;
#pragma unroll
        for (int mt = 0; mt < 2; mt++) {
#pragma unroll
            for (int r = 0; r < 4; r++) {
                int n = n0 + mt * 16 + qd * 4 + r;
                if (n < NN) {
#pragma unroll
                    for (int h2 = 0; h2 < 2; h2++) {
                        short4 pk4;
                        pk4.x = f2bf(acc[mt][h2 * 4 + 0][r] + bvals[h2 * 4 + 0]);
                        pk4.y = f2bf(acc[mt][h2 * 4 + 1][r] + bvals[h2 * 4 + 1]);
                        pk4.z = f2bf(acc[mt][h2 * 4 + 2][r] + bvals[h2 * 4 + 2]);
                        pk4.w = f2bf(acc[mt][h2 * 4 + 3][r] + bvals[h2 * 4 + 3]);
                        ((short4*)dstb)[(size_t)n * 32 + h2 * 16 + c] = pk4;
                    }
                }
            }
        }
    } else {
#pragma unroll
        for (int mt = 0; mt < 2; mt++) {
#pragma unroll
            for (int r = 0; r < 4; r++) {
                int n = n0 + mt * 16 + qd * 4 + r;
                if (n < NN) {
                    float* dp = skip + (size_t)n * HC + c;
#pragma unroll
                    for (int nt = 0; nt < 8; nt++)
                        dp[nt * 16] = acc[mt][nt][r] + bvals[nt];
                }
            }
        }
    }
}

// ---------------------------------------------------------------------------
// K2a: e-projection, original edge order, K=128 (Taylor time enc in
// epilogue). Sequential fragment-layout store [e][2][16][4]. (round-6)
// ---------------------------------------------------------------------------
__global__ __launch_bounds__(256) void eproj_kernel(
    const int*   __restrict__ ei,
    const float* __restrict__ tarr,
    const float* __restrict__ lastup,
    const float* __restrict__ msg,
    const short* __restrict__ WmT,      // [128][128] bf16 (n-major)
    const float* __restrict__ Apoly,    // [5][32] float4 fragment layout
    short* __restrict__ e_buf)          // [NE][2][16][4] bf16 fragment layout
{
    __shared__ short mg[TILE_E * PXS];  // 17.4 KB
    __shared__ float relt[TILE_E];

    const int t  = threadIdx.x;
    const int e0 = blockIdx.x * TILE_E;

    const int w    = t >> 6;
    const int h    = w >> 1;
    const int half = w & 1;
    const int lane = t & 63;
    const int qd   = lane >> 4;
    const int c    = lane & 15;
    const int hb   = h * 64;

    // issue Apoly loads early (in flight through staging + MFMA)
    const float4* Ap = (const float4*)Apoly;
    float4 A0 = Ap[0 * 32 + h * 16 + c];
    float4 A1 = Ap[1 * 32 + h * 16 + c];
    float4 A2 = Ap[2 * 32 + h * 16 + c];
    float4 A3 = Ap[3 * 32 + h * 16 + c];
    float4 A4 = Ap[4 * 32 + h * 16 + c];

    if (t < TILE_E) {
        int eg = e0 + t;
        float rt = 0.f;
        if (eg < NE) rt = tarr[eg] - lastup[ei[eg]];
        relt[t] = rt;
    }

    // --- batched staging: 8 float4 loads issued together, then convert ---
    float4 mreg[8];
#pragma unroll
    for (int j = 0; j < 8; j++) {
        int idx = t + j * 256;
        int le  = idx >> 5;
        int c4  = idx & 31;
        float4 m = {0.f, 0.f, 0.f, 0.f};
        if (e0 + le < NE) m = ((const float4*)msg)[(size_t)(e0 + le) * 32 + c4];
        mreg[j] = m;
    }
#pragma unroll
    for (int j = 0; j < 8; j++) {
        int idx = t + j * 256;
        int le  = idx >> 5;
        int c4  = idx & 31;
        int li  = le & 31;
        int row = (le & 32) + ((li & 7) >> 2) * 16 + (li >> 3) * 4 + (li & 3);
        short4 pm;
        pm.x = f2bf(mreg[j].x); pm.y = f2bf(mreg[j].y);
        pm.z = f2bf(mreg[j].z); pm.w = f2bf(mreg[j].w);
        *(short4*)&mg[row * PXS + 4 * c4] = pm;
    }
    __syncthreads();

    // --- preload A-fragments (8 ds_read_b128) ---
    bf16x8 a[2][4];
#pragma unroll
    for (int mt = 0; mt < 2; mt++)
#pragma unroll
        for (int kb2 = 0; kb2 < 4; kb2++)
            a[mt][kb2] = *(const bf16x8*)&mg[(half * 32 + mt * 16 + c) * PXS + qd * 8 + kb2 * 32];

    f32x4 acc[2][4];
#pragma unroll
    for (int mt = 0; mt < 2; mt++)
#pragma unroll
        for (int nt = 0; nt < 4; nt++) acc[mt][nt] = (f32x4){0.f, 0.f, 0.f, 0.f};

    const short* bP = &WmT[(size_t)(hb + c) * 128 + qd * 8];
#pragma unroll
    for (int nt = 0; nt < 4; nt++) {
        bf16x8 bw[4];
#pragma unroll
        for (int kb2 = 0; kb2 < 4; kb2++)
            bw[kb2] = *(const bf16x8*)(bP + (size_t)(nt * 16) * 128 + kb2 * 32);
#pragma unroll
        for (int kb2 = 0; kb2 < 4; kb2++) {
            acc[0][nt] = __builtin_amdgcn_mfma_f32_16x16x32_bf16(a[0][kb2], bw[kb2], acc[0][nt], 0, 0, 0);
            acc[1][nt] = __builtin_amdgcn_mfma_f32_16x16x32_bf16(a[1][kb2], bw[kb2], acc[1][nt], 0, 0, 0);
        }
    }

    // --- epilogue: Taylor time-encoding, sequential fragment store ---
#pragma unroll
    for (int mt = 0; mt < 2; mt++) {
#pragma unroll
        for (int r = 0; r < 4; r++) {
            int le = half * 32 + qd * 8 + mt * 4 + r;
            int eg = e0 + le;
            if (eg < NE) {
                float rt = relt[le];
                float w0 = A0.x + rt * (A1.x + rt * (A2.x + rt * (A3.x + rt * A4.x)));
                float w1 = A0.y + rt * (A1.y + rt * (A2.y + rt * (A3.y + rt * A4.y)));
                float w2 = A0.z + rt * (A1.z + rt * (A2.z + rt * (A3.z + rt * A4.z)));
                float w3 = A0.w + rt * (A1.w + rt * (A2.w + rt * (A3.w + rt * A4.w)));
                short4 o;
                o.x = f2bf(acc[mt][0][r] + w0);
                o.y = f2bf(acc[mt][1][r] + w1);
                o.z = f2bf(acc[mt][2][r] + w2);
                o.w = f2bf(acc[mt][3][r] + w3);
                ((short4*)e_buf)[(size_t)eg * 32 + h * 16 + c] = o;
            }
        }
    }
}

// ---------------------------------------------------------------------------
// K2b: node-centric attention (round-6 structure: 8 nodes/block, 16 lanes
// per (node, head)) + REGISTER-PREFETCHED edge list: first 16 edata entries
// loaded up front, then two fully-static masked batches of 8 edges with all
// 24 gathers issued address-ready. deg>16 falls back to memory loop.
// Zero atomics, finalize fused.
// ---------------------------------------------------------------------------
__device__ __forceinline__ void attn_edge_acc(
    short4 k1, short4 v1, short4 g1,
    float qf0, float qf1, float qf2, float qf3,
    float& a0, float& a1, float& a2, float& a3, float& asum, bool valid)
{
    float e0v = bf2f(g1.x), e1v = bf2f(g1.y), e2v = bf2f(g1.z), e3v = bf2f(g1.w);
    float p = qf0 * (bf2f(k1.x) + e0v) + qf1 * (bf2f(k1.y) + e1v)
            + qf2 * (bf2f(k1.z) + e2v) + qf3 * (bf2f(k1.w) + e3v);
    p += __shfl_xor(p, 1);
    p += __shfl_xor(p, 2);
    p += __shfl_xor(p, 4);
    p += __shfl_xor(p, 8);
    float al = __expf(p * 0.125f);   // 1/sqrt(64)
    if (valid) {
        a0 += (bf2f(v1.x) + e0v) * al;
        a1 += (bf2f(v1.y) + e1v) * al;
        a2 += (bf2f(v1.z) + e2v) * al;
        a3 += (bf2f(v1.w) + e3v) * al;
        asum += al;
    }
}

__global__ __launch_bounds__(256) void attn_node(
    const int2*  __restrict__ edata,
    const short* __restrict__ qb,       // fragment layout bf16 [n][2][16][4]
    const short* __restrict__ kb,
    const short* __restrict__ vb,
    const short* __restrict__ e_buf,    // fragment layout bf16, orig order
    const int*   __restrict__ cnt,
    const int*   __restrict__ cursor,   // post-scatter: start+cnt (chunk-local)
    const int*   __restrict__ bsum,
    const float* __restrict__ skip,
    float* __restrict__ out)
{
    const int t    = threadIdx.x;
    const int w    = t >> 6;
    const int h    = w & 1;
    const int lane = t & 63;
    const int qd   = lane >> 4;
    const int c    = lane & 15;
    const int n    = blockIdx.x * 8 + (w >> 1) * 4 + qd;   // 6250*8 = 50000 exact

    const int deg   = cnt[n];
    const int start = cursor[n] + bsum[n >> 11] - deg;

    short4 q4 = ((const short4*)qb)[(size_t)n * 32 + h * 16 + c];
    float qf0 = bf2f(q4.x), qf1 = bf2f(q4.y), qf2 = bf2f(q4.z), qf3 = bf2f(q4.w);

    float a0 = 0.f, a1 = 0.f, a2 = 0.f, a3 = 0.f, asum = 0.f;

    if (deg > 0) {
        // prefetch first 16 edge records (edata padded by +16)
        int2 ed[16];
#pragma unroll
        for (int j = 0; j < 16; j++) ed[j] = edata[start + j];

        const int nb = (deg < 16) ? deg : 16;

        // batch 1: edges 0..7 (static indices, masked accumulate)
        {
            short4 kx[8], vx[8], gx[8];
#pragma unroll
            for (int j = 0; j < 8; j++) {
                int s  = (j < nb) ? ed[j].x : ed[0].x;
                int eo = (j < nb) ? ed[j].y : ed[0].y;
                kx[j] = ((const short4*)kb)[(size_t)s * 32 + h * 16 + c];
                vx[j] = ((const short4*)vb)[(size_t)s * 32 + h * 16 + c];
                gx[j] = ((const short4*)e_buf)[(size_t)eo * 32 + h * 16 + c];
            }
#pragma unroll
            for (int j = 0; j < 8; j++)
                attn_edge_acc(kx[j], vx[j], gx[j], qf0, qf1, qf2, qf3,
                              a0, a1, a2, a3, asum, j < nb);
        }
        // batch 2: edges 8..15
        if (nb > 8) {
            short4 kx[8], vx[8], gx[8];
#pragma unroll
            for (int j = 0; j < 8; j++) {
                int jj = j + 8;
                int s  = (jj < nb) ? ed[jj].x : ed[0].x;
                int eo = (jj < nb) ? ed[jj].y : ed[0].y;
                kx[j] = ((const short4*)kb)[(size_t)s * 32 + h * 16 + c];
                vx[j] = ((const short4*)vb)[(size_t)s * 32 + h * 16 + c];
                gx[j] = ((const short4*)e_buf)[(size_t)eo * 32 + h * 16 + c];
            }
#pragma unroll
            for (int j = 0; j < 8; j++)
                attn_edge_acc(kx[j], vx[j], gx[j], qf0, qf1, qf2, qf3,
                              a0, a1, a2, a3, asum, (j + 8) < nb);
        }
        // overflow (deg > 16): memory loop, unroll 2
        int i = 16;
        for (; i + 2 <= deg; i += 2) {
            int2 eA = edata[start + i];
            int2 eB = edata[start + i + 1];
            short4 kA = ((const short4*)kb)[(size_t)eA.x * 32 + h * 16 + c];
            short4 vA = ((const short4*)vb)[(size_t)eA.x * 32 + h * 16 + c];
            short4 gA = ((const short4*)e_buf)[(size_t)eA.y * 32 + h * 16 + c];
            short4 kB = ((const short4*)kb)[(size_t)eB.x * 32 + h * 16 + c];
            short4 vB = ((const short4*)vb)[(size_t)eB.x * 32 + h * 16 + c];
            short4 gB = ((const short4*)e_buf)[(size_t)eB.y * 32 + h * 16 + c];
            attn_edge_acc(kA, vA, gA, qf0, qf1, qf2, qf3, a0, a1, a2, a3, asum, true);
            attn_edge_acc(kB, vB, gB, qf0, qf1, qf2, qf3, a0, a1, a2, a3, asum, true);
        }
        if (i < deg) {
            int2 eA = edata[start + i];
            short4 kA = ((const short4*)kb)[(size_t)eA.x * 32 + h * 16 + c];
            short4 vA = ((const short4*)vb)[(size_t)eA.x * 32 + h * 16 + c];
            short4 gA = ((const short4*)e_buf)[(size_t)eA.y * 32 + h * 16 + c];
            attn_edge_acc(kA, vA, gA, qf0, qf1, qf2, qf3, a0, a1, a2, a3, asum, true);
        }
    }

    float inv = 1.0f / (asum + 1e-16f);
    size_t ob = (size_t)n * HC + h * 64 + c;
    out[ob]      = a0 * inv + skip[ob];
    out[ob + 16] = a1 * inv + skip[ob + 16];
    out[ob + 32] = a2 * inv + skip[ob + 32];
    out[ob + 48] = a3 * inv + skip[ob + 48];
}

// ---------------------------------------------------------------------------
extern "C" void kernel_launch(void* const* d_in, const int* in_sizes, int n_in,
                              void* d_out, int out_size, void* d_ws, size_t ws_size,
                              hipStream_t stream) {
    const float* x      = (const float*)d_in[0];
    const float* lastup = (const float*)d_in[1];
    const float* tarr   = (const float*)d_in[2];
    const float* msg    = (const float*)d_in[3];
    const float* time_w = (const float*)d_in[4];
    const float* time_b = (const float*)d_in[5];
    const float* Wq     = (const float*)d_in[6];
    const float* bq     = (const float*)d_in[7];
    const float* Wk     = (const float*)d_in[8];
    const float* bk     = (const float*)d_in[9];
    const float* Wv     = (const float*)d_in[10];
    const float* bv     = (const float*)d_in[11];
    const float* We     = (const float*)d_in[12];
    const float* Wskip  = (const float*)d_in[13];
    const float* bskip  = (const float*)d_in[14];
    const int*   ei     = (const int*)d_in[15];

    // ws layout: skip f32 | Apoly f32 | edata int2 (NE+16) | WmT | WT |
    //            qb | kb | vb | e_buf bf16 | cnt | cursor | bsum (int)
    float* ws    = (float*)d_ws;
    float* skip  = ws;
    float* Apoly = skip + (size_t)NN * HC;
    int2*  edata = (int2*)(Apoly + 5 * 128);
    short* WmT   = (short*)(edata + (NE + 16));
    short* WT    = WmT + (size_t)HC * 128;
    short* qb    = WT + (size_t)4 * 128 * 128;
    short* kb    = qb + (size_t)NN * HC;
    short* vb    = kb + (size_t)NN * HC;
    short* e_buf = vb + (size_t)NN * HC;
    int*   cnt    = (int*)(e_buf + (size_t)NE * HC);
    int*   cursor = cnt + NN;
    int*   bsum   = cursor + NN;
    float* out  = (float*)d_out;

    // --- prep (+fused histogram) ---
    hipMemsetAsync(cnt, 0, (size_t)NN * sizeof(int), stream);
    prep_all<<<dim3((HC * 128 + 4 * 128 * 128 + NE + 255) / 256), 256, 0, stream>>>(
        We, Wq, Wk, Wv, Wskip, WmT, WT, ei, cnt);

    // --- counting sort by dst (int2 edata; coeffs + pad piggyback scan2) ---
    scan1<<<dim3(NSCAN), 256, 0, stream>>>(cnt, cursor, bsum);
    scan2<<<dim3(1), 128, 0, stream>>>(bsum, time_w, time_b, We, Apoly, edata);
    scatter_kernel<<<dim3((NE + 255) / 256), 256, 0, stream>>>(
        ei, cursor, bsum, edata);

    proj_mfma<<<dim3((NN + 31) / 32), 256, 0, stream>>>(
        x, WT, bq, bk, bv, bskip, qb, kb, vb, skip);

    // --- e projection: streaming msg, sequential fragment-layout write ---
    eproj_kernel<<<dim3((NE + TILE_E - 1) / TILE_E), 256, 0, stream>>>(
        ei, tarr, lastup, msg, WmT, Apoly, e_buf);

    // --- node-centric attention: register-prefetched edges, zero atomics ---
    attn_node<<<dim3(NN / 8), 256, 0, stream>>>(
        edata, qb, kb, vb, e_buf, cnt, cursor, bsum, skip, out);
}